// Round 2
// baseline (377.248 us; speedup 1.0000x reference)
//
#include <hip/hip_runtime.h>
#include <hip/hip_bf16.h>

// Problem constants (from reference): B=128, T=512, D_IN=512, D_OUT=512
// GEMM: C[M=65536][512] = X[M][512] . W[512][512]^T + bias, then LIF scan over T.
#define M_TOT 65536
#define K_DIM 512
#define N_DIM 512
#define T_STEPS 512
#define BETA 0.95f

#define BM 128
#define BN 128
#define BK 32

typedef __attribute__((ext_vector_type(8))) short bf16x8;
typedef __attribute__((ext_vector_type(4))) float f32x4;

static __device__ __forceinline__ unsigned short f2bf(float f) {
    unsigned int u = __float_as_uint(f);
    // round-to-nearest-even to bf16
    unsigned int r = (u + 0x7FFFu + ((u >> 16) & 1u)) >> 16;
    return (unsigned short)r;
}

__global__ __launch_bounds__(256) void gemm_currents(
    const float* __restrict__ X,   // [M_TOT][K_DIM]
    const float* __restrict__ W,   // [N_DIM][K_DIM]
    const float* __restrict__ bias,// [N_DIM]
    float* __restrict__ C)         // [M_TOT][N_DIM]
{
    __shared__ unsigned short Xs[BM][BK]; // bf16 bits, row stride 64B
    __shared__ unsigned short Ws[BN][BK];

    const int ntile = blockIdx.x;  // 0..3
    const int mtile = blockIdx.y;  // 0..511
    const int tid  = threadIdx.x;
    const int lane = tid & 63;
    const int wave = tid >> 6;     // 0..3
    const int wr = wave >> 1;      // 0..1
    const int wc = wave & 1;       // 0..1

    const int row0 = mtile * BM;
    const int col0 = ntile * BN;

    f32x4 acc[4][4] = {};

    const int frow = lane & 15;          // fragment row (A) / row-of-W (B)
    const int fk   = (lane >> 4) * 8;    // fragment k offset

    for (int k0 = 0; k0 < K_DIM; k0 += BK) {
        // ---- stage X,W tiles: 128 rows x 8 kgroups(4 floats) = 1024 slots, 4/thread
        #pragma unroll
        for (int i = 0; i < 4; ++i) {
            int slot = tid + i * 256;
            int r  = slot >> 3;
            int kg = (slot & 7) * 4;
            float4 xv = *(const float4*)(X + (size_t)(row0 + r) * K_DIM + k0 + kg);
            float4 wv = *(const float4*)(W + (size_t)(col0 + r) * K_DIM + k0 + kg);
            ushort4 xb, wb;
            xb.x = f2bf(xv.x); xb.y = f2bf(xv.y); xb.z = f2bf(xv.z); xb.w = f2bf(xv.w);
            wb.x = f2bf(wv.x); wb.y = f2bf(wv.y); wb.z = f2bf(wv.z); wb.w = f2bf(wv.w);
            *(ushort4*)(&Xs[r][kg]) = xb;
            *(ushort4*)(&Ws[r][kg]) = wb;
        }
        __syncthreads();

        // ---- fragment loads (8 contiguous bf16 = 16B each)
        bf16x8 afr[4], bfr[4];
        #pragma unroll
        for (int m = 0; m < 4; ++m)
            afr[m] = *(const bf16x8*)(&Xs[wr * 64 + m * 16 + frow][fk]);
        #pragma unroll
        for (int n = 0; n < 4; ++n)
            bfr[n] = *(const bf16x8*)(&Ws[wc * 64 + n * 16 + frow][fk]);

        #pragma unroll
        for (int m = 0; m < 4; ++m)
            #pragma unroll
            for (int n = 0; n < 4; ++n)
                acc[m][n] = __builtin_amdgcn_mfma_f32_16x16x32_bf16(
                    afr[m], bfr[n], acc[m][n], 0, 0, 0);
        __syncthreads();
    }

    // ---- epilogue: C/D layout col=lane&15, row=(lane>>4)*4+reg
    const int crow_base = (lane >> 4) * 4;
    const int ccol = lane & 15;
    #pragma unroll
    for (int n = 0; n < 4; ++n) {
        int col = col0 + wc * 64 + n * 16 + ccol;
        float bv = bias[col];
        #pragma unroll
        for (int m = 0; m < 4; ++m) {
            int rowb = row0 + wr * 64 + m * 16 + crow_base;
            #pragma unroll
            for (int r = 0; r < 4; ++r) {
                C[(size_t)(rowb + r) * N_DIM + col] = acc[m][n][r] + bv;
            }
        }
    }
}

__global__ void zero_sum(float* s) { *s = 0.0f; }

// One thread per neuron (b,d): sequential LIF over T, in-place currents -> spikes.
__global__ __launch_bounds__(256) void lif_scan(
    float* __restrict__ C,        // [B][T][D] currents in, spikes out
    float* __restrict__ sum_out)
{
    const int idx = blockIdx.x * 256 + threadIdx.x;  // 0..65535
    const int bb = idx >> 9;      // batch
    const int d  = idx & 511;     // neuron
    float* p = C + (size_t)bb * T_STEPS * N_DIM + d;

    float mem = 0.0f;
    int count = 0;
    for (int t = 0; t < T_STEPS; t += 8) {
        float cur[8];
        #pragma unroll
        for (int j = 0; j < 8; ++j)
            cur[j] = p[(size_t)(t + j) * N_DIM];
        #pragma unroll
        for (int j = 0; j < 8; ++j) {
            mem = BETA * mem + cur[j];
            float spk = (mem > 1.0f) ? 1.0f : 0.0f;
            mem -= spk;  // threshold = 1.0
            p[(size_t)(t + j) * N_DIM] = spk;
            count += (spk > 0.0f);
        }
    }

    // block-reduce spike count (exact integer arithmetic)
    #pragma unroll
    for (int off = 32; off > 0; off >>= 1)
        count += __shfl_down(count, off);
    __shared__ int wsum[4];
    if ((threadIdx.x & 63) == 0) wsum[threadIdx.x >> 6] = count;
    __syncthreads();
    if (threadIdx.x == 0) {
        int tot = wsum[0] + wsum[1] + wsum[2] + wsum[3];
        atomicAdd(sum_out, (float)tot);
    }
}

extern "C" void kernel_launch(void* const* d_in, const int* in_sizes, int n_in,
                              void* d_out, int out_size, void* d_ws, size_t ws_size,
                              hipStream_t stream) {
    const float* X    = (const float*)d_in[0];  // [128,512,512]
    const float* W    = (const float*)d_in[1];  // [512,512]
    const float* bias = (const float*)d_in[2];  // [512]
    float* out = (float*)d_out;                 // [128*512*512] spikes + [1] sum

    dim3 grid(N_DIM / BN, M_TOT / BM);          // (4, 512)
    gemm_currents<<<grid, 256, 0, stream>>>(X, W, bias, out);
    zero_sum<<<1, 1, 0, stream>>>(out + (size_t)M_TOT * N_DIM);
    lif_scan<<<M_TOT / 256, 256, 0, stream>>>(out, out + (size_t)M_TOT * N_DIM);
}

// Round 4
// 333.305 us; speedup vs baseline: 1.1318x; 1.1318x over previous
//
#include <hip/hip_runtime.h>
#include <hip/hip_bf16.h>

// B=128, T=512, D_IN=512, D_OUT=512
// currents[M=65536][512] = X[M][512] . W[512][512]^T + bias ; then LIF scan over T.
#define M_TOT 65536
#define K_DIM 512
#define N_DIM 512
#define T_STEPS 512
#define BETA 0.95f

#define BM 128
#define BN 128
#define BK 64

typedef __attribute__((ext_vector_type(8))) short bf16x8;
typedef __attribute__((ext_vector_type(4))) float f32x4;

static __device__ __forceinline__ unsigned short f2bf(float f) {
    // Let the compiler emit v_cvt_pk_bf16_f32 (RNE) — do NOT hand-roll bit math.
    __hip_bfloat16 h = __float2bfloat16(f);
    return __builtin_bit_cast(unsigned short, h);
}

__global__ __launch_bounds__(256) void gemm_currents(
    const float* __restrict__ X,   // [M_TOT][K_DIM]
    const float* __restrict__ W,   // [N_DIM][K_DIM]
    const float* __restrict__ bias,// [N_DIM]
    float* __restrict__ C)         // [M_TOT][N_DIM]
{
    // bf16 tiles, XOR-swizzled at 8B-group granularity: group g' = g ^ 2*(row&7)
    __shared__ unsigned short Xs[BM][BK]; // 16 KB
    __shared__ unsigned short Ws[BN][BK]; // 16 KB

    // XCD-bijective swizzle (2048 blocks % 8 == 0): 4 n-tiles of one m-tile
    // stay on one XCD -> X panel fetched once per XCD L2.
    const int lin  = blockIdx.x;            // 0..2047
    const int swz  = (lin & 7) * 256 + (lin >> 3);
    const int mtile = swz >> 2;             // 0..511
    const int ntile = swz & 3;              // 0..3

    const int tid  = threadIdx.x;
    const int lane = tid & 63;
    const int wave = tid >> 6;     // 0..3
    const int wr = wave >> 1;      // 0..1
    const int wc = wave & 1;       // 0..1

    const int row0 = mtile * BM;
    const int col0 = ntile * BN;

    f32x4 acc[4][4] = {};

    // staging geometry: 128 rows x 16 kgroups(float4) = 2048 slots, 8/thread
    const int sr0 = tid >> 4;          // row advances by 16 per i-step
    const int skg = (tid & 15) << 2;   // element offset of this thread's float4

    for (int k0 = 0; k0 < K_DIM; k0 += BK) {
        #pragma unroll
        for (int i = 0; i < 8; ++i) {
            int r  = sr0 + i * 16;
            int kgs = skg ^ ((r & 7) << 3);   // 8B-group XOR swizzle
            float4 xv = *(const float4*)(X + (size_t)(row0 + r) * K_DIM + k0 + skg);
            float4 wv = *(const float4*)(W + (size_t)(col0 + r) * K_DIM + k0 + skg);
            ushort4 xb, wb;
            xb.x = f2bf(xv.x); xb.y = f2bf(xv.y); xb.z = f2bf(xv.z); xb.w = f2bf(xv.w);
            wb.x = f2bf(wv.x); wb.y = f2bf(wv.y); wb.z = f2bf(wv.z); wb.w = f2bf(wv.w);
            *(ushort4*)(&Xs[r][kgs]) = xb;
            *(ushort4*)(&Ws[r][kgs]) = wb;
        }
        __syncthreads();

        const int frow = lane & 15;
        const int cblk = lane >> 4;        // 16B block within k-half
        #pragma unroll
        for (int kh = 0; kh < 2; ++kh) {
            bf16x8 afr[4], bfr[4];
            #pragma unroll
            for (int m = 0; m < 4; ++m) {
                int row = wr * 64 + m * 16 + frow;
                int c = (kh * 4 + cblk) ^ (row & 7);
                afr[m] = *(const bf16x8*)(&Xs[row][c * 8]);
            }
            #pragma unroll
            for (int n = 0; n < 4; ++n) {
                int row = wc * 64 + n * 16 + frow;
                int c = (kh * 4 + cblk) ^ (row & 7);
                bfr[n] = *(const bf16x8*)(&Ws[row][c * 8]);
            }
            #pragma unroll
            for (int m = 0; m < 4; ++m)
                #pragma unroll
                for (int n = 0; n < 4; ++n)
                    acc[m][n] = __builtin_amdgcn_mfma_f32_16x16x32_bf16(
                        afr[m], bfr[n], acc[m][n], 0, 0, 0);
        }
        __syncthreads();
    }

    // epilogue: C/D layout col=lane&15, row=(lane>>4)*4+reg
    const int crow_base = (lane >> 4) * 4;
    const int ccol = lane & 15;
    #pragma unroll
    for (int n = 0; n < 4; ++n) {
        int col = col0 + wc * 64 + n * 16 + ccol;
        float bv = bias[col];
        #pragma unroll
        for (int m = 0; m < 4; ++m) {
            int rowb = row0 + wr * 64 + m * 16 + crow_base;
            #pragma unroll
            for (int r = 0; r < 4; ++r) {
                C[(size_t)(rowb + r) * N_DIM + col] = acc[m][n][r] + bv;
            }
        }
    }
}

__global__ void zero_sum(float* s) { *s = 0.0f; }

// One thread per neuron chain (b,d). Two-buffer register pipeline keeps one
// 8-load batch in flight during every compute phase (latency hiding at the
// structural 1-wave/SIMD occupancy).
__global__ __launch_bounds__(256) void lif_scan(
    float* __restrict__ C,        // [B][T][D] currents in, spikes out (in place)
    float* __restrict__ sum_out)
{
    const int idx = blockIdx.x * 256 + threadIdx.x;  // 0..65535
    float* p = C + (size_t)(idx >> 9) * (T_STEPS * N_DIM) + (idx & 511);

    float mem = 0.0f;
    int count = 0;
    float a[8], b[8];

    #pragma unroll
    for (int j = 0; j < 8; ++j)
        a[j] = __builtin_nontemporal_load(p + (size_t)j * N_DIM);

    for (int t = 0; t < T_STEPS; t += 16) {
        #pragma unroll
        for (int j = 0; j < 8; ++j)
            b[j] = __builtin_nontemporal_load(p + (size_t)(t + 8 + j) * N_DIM);
        #pragma unroll
        for (int j = 0; j < 8; ++j) {
            mem = BETA * mem + a[j];
            float spk = (mem > 1.0f) ? 1.0f : 0.0f;
            mem -= spk;
            __builtin_nontemporal_store(spk, p + (size_t)(t + j) * N_DIM);
            count += (int)spk;
        }
        if (t + 16 < T_STEPS) {
            #pragma unroll
            for (int j = 0; j < 8; ++j)
                a[j] = __builtin_nontemporal_load(p + (size_t)(t + 16 + j) * N_DIM);
        }
        #pragma unroll
        for (int j = 0; j < 8; ++j) {
            mem = BETA * mem + b[j];
            float spk = (mem > 1.0f) ? 1.0f : 0.0f;
            mem -= spk;
            __builtin_nontemporal_store(spk, p + (size_t)(t + 8 + j) * N_DIM);
            count += (int)spk;
        }
    }

    // block-reduce spike count (exact integer arithmetic)
    #pragma unroll
    for (int off = 32; off > 0; off >>= 1)
        count += __shfl_down(count, off);
    __shared__ int wsum[4];
    if ((threadIdx.x & 63) == 0) wsum[threadIdx.x >> 6] = count;
    __syncthreads();
    if (threadIdx.x == 0) {
        int tot = wsum[0] + wsum[1] + wsum[2] + wsum[3];
        atomicAdd(sum_out, (float)tot);
    }
}

extern "C" void kernel_launch(void* const* d_in, const int* in_sizes, int n_in,
                              void* d_out, int out_size, void* d_ws, size_t ws_size,
                              hipStream_t stream) {
    const float* X    = (const float*)d_in[0];  // [128,512,512]
    const float* W    = (const float*)d_in[1];  // [512,512]
    const float* bias = (const float*)d_in[2];  // [512]
    float* out = (float*)d_out;                 // [128*512*512] spikes + [1] sum

    gemm_currents<<<(M_TOT / BM) * (N_DIM / BN), 256, 0, stream>>>(X, W, bias, out);
    zero_sum<<<1, 1, 0, stream>>>(out + (size_t)M_TOT * N_DIM);
    lif_scan<<<M_TOT / 256, 256, 0, stream>>>(out, out + (size_t)M_TOT * N_DIM);
}